// Round 8
// baseline (412.514 us; speedup 1.0000x reference)
//
#include <hip/hip_runtime.h>

#define D_MODEL 1024
#define D_FFN   4096
#define SEQ     2048
#define NROWS   4096   // B*S
#define QKV_LD  3072

typedef __bf16 bf16x8 __attribute__((ext_vector_type(8)));
typedef float  floatx4 __attribute__((ext_vector_type(4)));

__device__ __forceinline__ unsigned short f2bf(float f) {
  unsigned int u = __float_as_uint(f);
  u += 0x7FFFu + ((u >> 16) & 1u);   // RNE
  return (unsigned short)(u >> 16);
}

// DPP row_ror<N> within 16-lane rows (VALU-speed cross-lane; no LDS pipe)
template <int C>
__device__ __forceinline__ float ror16(float x) {
  return __int_as_float(
      __builtin_amdgcn_mov_dpp(__float_as_int(x), 0x120 | C, 0xf, 0xf, true));
}

// async global->LDS, 16B per lane. LDS dest = wave-uniform base + lane*16.
__device__ __forceinline__ void async16(const unsigned short* g, unsigned short* l) {
  __builtin_amdgcn_global_load_lds(
      (const __attribute__((address_space(1))) unsigned int*)g,
      (__attribute__((address_space(3))) unsigned int*)l, 16, 0, 0);
}

// ---------------- fp32 -> bf16 elementwise ----------------
__global__ __launch_bounds__(256) void k_f32_to_bf16(
    const float* __restrict__ in, unsigned short* __restrict__ outp, long n) {
  long i = ((long)blockIdx.x * 256 + threadIdx.x) * 4;
  if (i >= n) return;
  float4 v = *(const float4*)(in + i);
  ushort4 o;
  o.x = f2bf(v.x); o.y = f2bf(v.y); o.z = f2bf(v.z); o.w = f2bf(v.w);
  *(ushort4*)(outp + i) = o;
}

// ------------- transpose+convert: W[R][C] f32 -> WT[C][R] bf16 -------------
__global__ __launch_bounds__(256) void k_transpose_bf16(
    const float* __restrict__ W, unsigned short* __restrict__ WT, int R, int C) {
  __shared__ float tile[32][33];
  int tx = threadIdx.x & 31, ty = threadIdx.x >> 5;
  long bx = (long)blockIdx.x * 32;
  long by = (long)blockIdx.y * 32;
  #pragma unroll
  for (int j = 0; j < 4; j++)
    tile[ty + j * 8][tx] = W[(by + ty + j * 8) * C + bx + tx];
  __syncthreads();
  #pragma unroll
  for (int j = 0; j < 4; j++)
    WT[(bx + ty + j * 8) * R + by + tx] = f2bf(tile[tx][ty + j * 8]);
}

// ------------- 1024x1024 weight transposes fused (z: Wq,Wk,Wv -> WqkvT; Wo -> WoT) ------
__global__ __launch_bounds__(256) void k_transpose_sq(
    const float* __restrict__ Wq, const float* __restrict__ Wk,
    const float* __restrict__ Wv, const float* __restrict__ Wo,
    unsigned short* __restrict__ WqkvT, unsigned short* __restrict__ WoT) {
  __shared__ float tile[32][33];
  int z = blockIdx.z;
  const float* W = (z == 0) ? Wq : (z == 1) ? Wk : (z == 2) ? Wv : Wo;
  unsigned short* dst = (z < 3) ? (WqkvT + (size_t)z * D_MODEL * D_MODEL) : WoT;
  int tx = threadIdx.x & 31, ty = threadIdx.x >> 5;
  long bx = (long)blockIdx.x * 32;
  long by = (long)blockIdx.y * 32;
  #pragma unroll
  for (int j = 0; j < 4; j++)
    tile[ty + j * 8][tx] = W[(by + ty + j * 8) * D_MODEL + bx + tx];
  __syncthreads();
  #pragma unroll
  for (int j = 0; j < 4; j++)
    dst[(bx + ty + j * 8) * D_MODEL + by + tx] = f2bf(tile[tx][ty + j * 8]);
}

__global__ __launch_bounds__(256) void k_pack_bias(
    const float* __restrict__ bq, const float* __restrict__ bk,
    const float* __restrict__ bv, float* __restrict__ dst) {
  int i = blockIdx.x * 256 + threadIdx.x;
  if (i >= 3072) return;
  float v = (i < 1024) ? bq[i] : (i < 2048) ? bk[i - 1024] : bv[i - 2048];
  dst[i] = v;
}

// ------------- V^T: QKV[:, 2048+d] -> Vt[d][row]  (bf16) -------------
__global__ __launch_bounds__(256) void k_transpose_v(
    const unsigned short* __restrict__ QKV, unsigned short* __restrict__ Vt) {
  __shared__ unsigned short tile[64][72];
  int r0 = blockIdx.x * 64;
  int c0 = blockIdx.y * 64;
  int tx = threadIdx.x & 15, ty = threadIdx.x >> 4;
  #pragma unroll
  for (int j = 0; j < 4; j++) {
    int r = ty + j * 16;
    *(ushort4*)&tile[r][tx * 4] =
        *(const ushort4*)(QKV + (long)(r0 + r) * QKV_LD + 2048 + c0 + tx * 4);
  }
  __syncthreads();
  #pragma unroll
  for (int j = 0; j < 4; j++) {
    int d = ty + j * 16;
    ushort4 o;
    o.x = tile[tx * 4 + 0][d];
    o.y = tile[tx * 4 + 1][d];
    o.z = tile[tx * 4 + 2][d];
    o.w = tile[tx * 4 + 3][d];
    *(ushort4*)(Vt + (long)(c0 + d) * NROWS + r0 + tx * 4) = o;
  }
}

// ---------------- bf16 MFMA GEMM: BK=32, double-buffered LDS ping-pong ----------------
// C[M][N] = A[M][K] @ Bt[N][K]^T + bias. 128x128 tile. flags: bit0 f32out, bit1 relu.
// Pipeline: barrier -> stage(next buf) -> compute(cur buf). The compiler's
// vmcnt(0)-before-barrier then waits on loads issued a full compute-phase ago.
// 16B chunk c of row r stored at position c^(r&3): frag reads are 4-way (1.58x)
// instead of 8-way (2.94x); staging stays global_load_lds-legal.
__global__ __launch_bounds__(256) void k_gemm(
    const unsigned short* __restrict__ A,
    const unsigned short* __restrict__ Bt,
    const float* __restrict__ bias,
    void* __restrict__ Cp, int M, int N, int K, int flags) {
  __shared__ unsigned short As[2][128 * 32];
  __shared__ unsigned short Bs[2][128 * 32];
  int tid = threadIdx.x, lane = tid & 63, wave = tid >> 6;
  int quad = lane >> 4, l16 = lane & 15;
  int wm = (wave & 1) * 64, wn = (wave >> 1) * 64;
  long bm = (long)blockIdx.x * 128;
  long bn = (long)blockIdx.y * 128;
  int nz = gridDim.z, z = blockIdx.z;
  int Ks = K / nz;
  long zb = (long)z * Ks;

  const floatx4 fz = {0.f, 0.f, 0.f, 0.f};
  floatx4 acc[4][4];
  #pragma unroll
  for (int i = 0; i < 4; i++)
    #pragma unroll
    for (int j = 0; j < 4; j++) acc[i][j] = fz;

  // staging: each wave-instr covers 16 rows x 64B; lane -> row srow, chunk pos lane&3
  // holding global chunk (lane&3)^(srow&3).
  int srow = lane >> 2;
  int c0 = (lane & 3) ^ (srow & 3);
  int r0 = wave * 16 + srow;                 // + j*64 (64 = 0 mod 4, swizzle invariant)
  const unsigned short* Ag = A + (bm + r0) * (long)K + zb + c0 * 8;
  const unsigned short* Bg = Bt + (bn + r0) * (long)K + zb + c0 * 8;

  auto stage = [&](int b, int k0) {
    async16(Ag + k0, As[b] + (wave * 16) * 32);
    async16(Ag + (long)64 * K + k0, As[b] + (wave * 16 + 64) * 32);
    async16(Bg + k0, Bs[b] + (wave * 16) * 32);
    async16(Bg + (long)64 * K + k0, Bs[b] + (wave * 16 + 64) * 32);
  };

  stage(0, 0);
  int cur = 0;
  for (int k0 = 0; k0 < Ks; k0 += 32) {
    __syncthreads();                    // cur staged; all waves done reading cur^1
    if (k0 + 32 < Ks) stage(cur ^ 1, k0 + 32);
    bf16x8 af[4], bfr[4];
    #pragma unroll
    for (int i = 0; i < 4; i++) {
      int r = wm + i * 16 + l16;
      af[i] = *(const bf16x8*)(As[cur] + r * 32 + (quad ^ (r & 3)) * 8);
    }
    #pragma unroll
    for (int j = 0; j < 4; j++) {
      int r = wn + j * 16 + l16;
      bfr[j] = *(const bf16x8*)(Bs[cur] + r * 32 + (quad ^ (r & 3)) * 8);
    }
    #pragma unroll
    for (int i = 0; i < 4; i++)
      #pragma unroll
      for (int j = 0; j < 4; j++)
        acc[i][j] = __builtin_amdgcn_mfma_f32_16x16x32_bf16(af[i], bfr[j], acc[i][j], 0, 0, 0);
    cur ^= 1;
  }

  bool f32out = (flags & 1) != 0;
  bool relu   = (flags & 2) != 0;
  float* outf = (float*)Cp + (size_t)z * M * (size_t)N;
  #pragma unroll
  for (int j = 0; j < 4; j++) {
    long col = bn + wn + j * 16 + l16;
    float bvv = (z == 0) ? bias[col] : 0.0f;
    #pragma unroll
    for (int i = 0; i < 4; i++) {
      long row = bm + wm + i * 16 + quad * 4;
      #pragma unroll
      for (int r = 0; r < 4; r++) {
        float v = acc[i][j][r] + bvv;
        if (relu) v = fmaxf(v, 0.0f);
        if (f32out) outf[(row + r) * (long)N + col] = v;
        else        ((unsigned short*)Cp)[(row + r) * (long)N + col] = f2bf(v);
      }
    }
  }
}

// ---------------- flash attention (causal), LDS-staged K/V ----------------
#define PLD 72
__global__ __launch_bounds__(256) void k_attn(
    const unsigned short* __restrict__ QKV,
    const unsigned short* __restrict__ Vt,
    unsigned short* __restrict__ Omat) {
  __shared__ unsigned short Ks[64 * 64];   // [kv][d], chunk-swizzled
  __shared__ unsigned short Vs[64 * 64];   // [d][kv], chunk-swizzled
  __shared__ unsigned short Ps[4][16 * PLD];
  int tid = threadIdx.x;
  int lane = tid & 63, wave = tid >> 6;
  int quad = lane >> 4, l16 = lane & 15;
  int z = blockIdx.x;
  int bh = z & 31;
  int qp = z >> 5;                 // 0..15
  int b = bh >> 4, h = bh & 15;
  long rowbase = (long)b * SEQ;
  int hd0 = h * 64;
  unsigned short* pw = &Ps[wave][0];
  const float SCL = 0.18033688f;   // 0.125 * log2(e)
  const floatx4 fz = {0.f, 0.f, 0.f, 0.f};

  int r_in = lane >> 3;
  int cpos = lane & 7;

  bf16x8 ones;
  #pragma unroll
  for (int i = 0; i < 8; i++) ones[i] = (__bf16)1.0f;

  #pragma unroll
  for (int phase = 0; phase < 2; phase++) {
    int qt = phase ? qp : (31 - qp);
    int q0w = qt * 64 + wave * 16;
    int qrow = q0w + quad * 4;
    int ntiles = qt + 1;

    bf16x8 qf0, qf1;
    {
      const unsigned short* qp_ =
          QKV + (rowbase + q0w + l16) * (long)QKV_LD + hd0 + quad * 8;
      qf0 = *(const bf16x8*)(qp_);
      qf1 = *(const bf16x8*)(qp_ + 32);
    }

    floatx4 ao[4], aol;
    #pragma unroll
    for (int t = 0; t < 4; t++) ao[t] = fz;
    aol = fz;
    float m_i[4];
    #pragma unroll
    for (int r = 0; r < 4; r++) m_i[r] = -3.0e38f;

    for (int it = 0; it < ntiles; it++) {
      int kv0 = it << 6;
      #pragma unroll
      for (int jj = 0; jj < 2; jj++) {
        int j = wave * 2 + jj;
        int r = j * 8 + r_in;
        int c = cpos ^ (r & 7);
        const unsigned short* gk =
            QKV + (rowbase + kv0 + r) * (long)QKV_LD + 1024 + hd0 + c * 8;
        async16(gk, Ks + j * 512);
        const unsigned short* gv =
            Vt + (long)(hd0 + r) * NROWS + rowbase + kv0 + c * 8;
        async16(gv, Vs + j * 512);
      }
      __syncthreads();

      floatx4 sacc[4];
      #pragma unroll
      for (int t = 0; t < 4; t++) {
        int row = t * 16 + l16;
        int sw = row & 7;
        bf16x8 kf0 = *(const bf16x8*)(Ks + row * 64 + (quad ^ sw) * 8);
        bf16x8 kf1 = *(const bf16x8*)(Ks + row * 64 + ((quad + 4) ^ sw) * 8);
        sacc[t] = __builtin_amdgcn_mfma_f32_16x16x32_bf16(qf0, kf0, fz, 0, 0, 0);
        sacc[t] = __builtin_amdgcn_mfma_f32_16x16x32_bf16(qf1, kf1, sacc[t], 0, 0, 0);
      }

      bool maskt = (it == ntiles - 1);
      if (maskt) {
        #pragma unroll
        for (int t = 0; t < 4; t++) {
          int kvc = kv0 + t * 16 + l16;
          #pragma unroll
          for (int r = 0; r < 4; r++) {
            float s = sacc[t][r] * SCL;
            sacc[t][r] = (kvc > qrow + r) ? -1.0e30f : s;
          }
        }
      } else {
        #pragma unroll
        for (int t = 0; t < 4; t++)
          #pragma unroll
          for (int r = 0; r < 4; r++) sacc[t][r] *= SCL;
      }

      float Mg = sacc[0][0];
      #pragma unroll
      for (int t = 0; t < 4; t++)
        #pragma unroll
        for (int r = 0; r < 4; r++) Mg = fmaxf(Mg, sacc[t][r]);
      Mg = fmaxf(Mg, ror16<1>(Mg));
      Mg = fmaxf(Mg, ror16<2>(Mg));
      Mg = fmaxf(Mg, ror16<4>(Mg));
      Mg = fmaxf(Mg, ror16<8>(Mg));

      float alpha[4];
      #pragma unroll
      for (int r = 0; r < 4; r++) {
        float mn = fmaxf(m_i[r], Mg);
        alpha[r] = __builtin_amdgcn_exp2f(m_i[r] - mn);
        m_i[r] = mn;
      }

      #pragma unroll
      for (int t = 0; t < 4; t++)
        #pragma unroll
        for (int r = 0; r < 4; r++) {
          float p = __builtin_amdgcn_exp2f(sacc[t][r] - m_i[r]);
          pw[(quad * 4 + r) * PLD + t * 16 + l16] =
              (unsigned short)(__float_as_uint(p) >> 16);
        }

      #pragma unroll
      for (int t = 0; t < 4; t++)
        #pragma unroll
        for (int r = 0; r < 4; r++) ao[t][r] *= alpha[r];
      #pragma unroll
      for (int r = 0; r < 4; r++) aol[r] *= alpha[r];

      __asm__ volatile("s_waitcnt lgkmcnt(0)" ::: "memory");
      bf16x8 pf0 = *(const bf16x8*)(pw + l16 * PLD + quad * 8);
      bf16x8 pf1 = *(const bf16x8*)(pw + l16 * PLD + 32 + quad * 8);

      #pragma unroll
      for (int t = 0; t < 4; t++) {
        int row = t * 16 + l16;
        int sw = row & 7;
        bf16x8 vf0 = *(const bf16x8*)(Vs + row * 64 + (quad ^ sw) * 8);
        bf16x8 vf1 = *(const bf16x8*)(Vs + row * 64 + ((quad + 4) ^ sw) * 8);
        ao[t] = __builtin_amdgcn_mfma_f32_16x16x32_bf16(pf0, vf0, ao[t], 0, 0, 0);
        ao[t] = __builtin_amdgcn_mfma_f32_16x16x32_bf16(pf1, vf1, ao[t], 0, 0, 0);
      }
      aol = __builtin_amdgcn_mfma_f32_16x16x32_bf16(pf0, ones, aol, 0, 0, 0);
      aol = __builtin_amdgcn_mfma_f32_16x16x32_bf16(pf1, ones, aol, 0, 0, 0);

      __syncthreads();
    }

    float inv[4];
    #pragma unroll
    for (int r = 0; r < 4; r++) inv[r] = 1.0f / aol[r];
    #pragma unroll
    for (int t = 0; t < 4; t++)
      #pragma unroll
      for (int r = 0; r < 4; r++)
        Omat[(rowbase + qrow + r) * (long)D_MODEL + hd0 + t * 16 + l16] =
            f2bf(ao[t][r] * inv[r]);
  }
}

// ------------- fused residual add (x + sum of np partial slabs) + layernorm -------------
__global__ __launch_bounds__(256) void k_add_ln(
    const float* __restrict__ A, const float* __restrict__ P, int np,
    const float* __restrict__ g, const float* __restrict__ be,
    float* __restrict__ Y, unsigned short* __restrict__ Ybf) {
  __shared__ float sb[4], ssb[4];
  int tid = threadIdx.x;
  long base = (long)blockIdx.x * D_MODEL + tid * 4;
  float4 a = *(const float4*)(A + base);
  float v0 = a.x, v1 = a.y, v2 = a.z, v3 = a.w;
  #pragma unroll 4
  for (int p = 0; p < np; p++) {
    float4 r = *(const float4*)(P + (size_t)p * NROWS * D_MODEL + base);
    v0 += r.x; v1 += r.y; v2 += r.z; v3 += r.w;
  }
  float s  = v0 + v1 + v2 + v3;
  float ss = v0 * v0 + v1 * v1 + v2 * v2 + v3 * v3;
  #pragma unroll
  for (int o = 32; o >= 1; o >>= 1) {
    s  += __shfl_xor(s, o, 64);
    ss += __shfl_xor(ss, o, 64);
  }
  int wave = tid >> 6;
  if ((tid & 63) == 0) { sb[wave] = s; ssb[wave] = ss; }
  __syncthreads();
  s  = sb[0] + sb[1] + sb[2] + sb[3];
  ss = ssb[0] + ssb[1] + ssb[2] + ssb[3];
  float mu  = s * (1.0f / 1024.0f);
  float var = ss * (1.0f / 1024.0f) - mu * mu;
  float rstd = rsqrtf(var + 1e-6f);
  float4 gv  = *(const float4*)(g + tid * 4);
  float4 bev = *(const float4*)(be + tid * 4);
  float o0 = (v0 - mu) * rstd * gv.x + bev.x;
  float o1 = (v1 - mu) * rstd * gv.y + bev.y;
  float o2 = (v2 - mu) * rstd * gv.z + bev.z;
  float o3 = (v3 - mu) * rstd * gv.w + bev.w;
  if (Y) *(float4*)(Y + base) = make_float4(o0, o1, o2, o3);
  if (Ybf) {
    ushort4 u;
    u.x = f2bf(o0); u.y = f2bf(o1); u.z = f2bf(o2); u.w = f2bf(o3);
    *(ushort4*)(Ybf + base) = u;
  }
}

extern "C" void kernel_launch(void* const* d_in, const int* in_sizes, int n_in,
                              void* d_out, int out_size, void* d_ws, size_t ws_size,
                              hipStream_t stream) {
  (void)in_sizes; (void)n_in; (void)out_size; (void)ws_size;
  const float* x   = (const float*)d_in[0];
  const float* Wq  = (const float*)d_in[1];
  const float* bq  = (const float*)d_in[2];
  const float* Wk  = (const float*)d_in[3];
  const float* bk  = (const float*)d_in[4];
  const float* Wv  = (const float*)d_in[5];
  const float* bv  = (const float*)d_in[6];
  const float* Wo  = (const float*)d_in[7];
  const float* bo  = (const float*)d_in[8];
  const float* g1  = (const float*)d_in[9];
  const float* b1  = (const float*)d_in[10];
  const float* Wup = (const float*)d_in[11];
  const float* bup = (const float*)d_in[12];
  const float* Wdn = (const float*)d_in[13];
  const float* bdn = (const float*)d_in[14];
  const float* g2  = (const float*)d_in[15];
  const float* b2  = (const float*)d_in[16];
  float* out = (float*)d_out;

  char* ws = (char*)d_ws;
  size_t off = 0;
  auto alloc = [&](size_t bytes) {
    char* p = ws + off;
    off = (off + bytes + 255) & ~(size_t)255;
    return p;
  };
  unsigned short* x_bf   = (unsigned short*)alloc((size_t)NROWS * D_MODEL * 2);
  unsigned short* WqkvT  = (unsigned short*)alloc((size_t)QKV_LD * D_MODEL * 2);
  unsigned short* WoT    = (unsigned short*)alloc((size_t)D_MODEL * D_MODEL * 2);
  unsigned short* WupT   = (unsigned short*)alloc((size_t)D_FFN * D_MODEL * 2);
  unsigned short* WdnT   = (unsigned short*)alloc((size_t)D_MODEL * D_FFN * 2);
  float*          bqkv   = (float*)alloc((size_t)QKV_LD * 4);
  float*          x1f    = (float*)alloc((size_t)NROWS * D_MODEL * 4);
  unsigned short* x1bf   = (unsigned short*)alloc((size_t)NROWS * D_MODEL * 2);
  // 64 MB region R: first holds qkv_bf (24MB) + Vt (8MB); after attention it is
  // reused for 4 split-K partial slabs (4 x 16MB) of Wo, then of FFN-down.
  float*          R      = (float*)alloc((size_t)4 * NROWS * D_MODEL * 4);
  unsigned short* qkv_bf = (unsigned short*)R;
  unsigned short* Vt     = (unsigned short*)((char*)R + (size_t)NROWS * QKV_LD * 2);
  unsigned short* mid_bf = (unsigned short*)alloc((size_t)NROWS * D_MODEL * 2);
  unsigned short* h_bf   = (unsigned short*)alloc((size_t)NROWS * D_FFN * 2);

  k_f32_to_bf16<<<4096, 256, 0, stream>>>(x, x_bf, (long)NROWS * D_MODEL);
  k_transpose_sq<<<dim3(32, 32, 4), 256, 0, stream>>>(Wq, Wk, Wv, Wo, WqkvT, WoT);
  k_transpose_bf16<<<dim3(128, 32), 256, 0, stream>>>(Wup, WupT, D_MODEL, D_FFN);
  k_transpose_bf16<<<dim3(32, 128), 256, 0, stream>>>(Wdn, WdnT, D_FFN, D_MODEL);
  k_pack_bias<<<12, 256, 0, stream>>>(bq, bk, bv, bqkv);

  // QKV projection (merged): [4096][3072] bf16
  k_gemm<<<dim3(32, 24), 256, 0, stream>>>(x_bf, WqkvT, bqkv, qkv_bf,
                                           NROWS, QKV_LD, D_MODEL, 0);
  k_transpose_v<<<dim3(64, 16), 256, 0, stream>>>(qkv_bf, Vt);

  k_attn<<<512, 256, 0, stream>>>(qkv_bf, Vt, mid_bf);

  // attention out-proj, split-K=4 -> f32 partials in R (qkv/Vt now dead)
  k_gemm<<<dim3(32, 8, 4), 256, 0, stream>>>(mid_bf, WoT, bo, R,
                                             NROWS, D_MODEL, D_MODEL, 1);
  k_add_ln<<<4096, 256, 0, stream>>>(x, R, 4, g1, b1, x1f, x1bf);

  // FFN up (relu, bf16 out)
  k_gemm<<<dim3(32, 32), 256, 0, stream>>>(x1bf, WupT, bup, h_bf,
                                           NROWS, D_FFN, D_MODEL, 2);
  // FFN down, split-K=4 -> f32 partials in R (Wo partials dead)
  k_gemm<<<dim3(32, 8, 4), 256, 0, stream>>>(h_bf, WdnT, bdn, R,
                                             NROWS, D_MODEL, D_FFN, 1);
  k_add_ln<<<4096, 256, 0, stream>>>(x1f, R, 4, g2, b2, out, nullptr);
}